// Round 4
// baseline (979.994 us; speedup 1.0000x reference)
//
#include <hip/hip_runtime.h>
#include <stdint.h>

typedef unsigned short ushort_t;
typedef __attribute__((ext_vector_type(8))) short bf16x8;
typedef __attribute__((ext_vector_type(4))) float f32x4;
typedef __attribute__((ext_vector_type(8))) unsigned short u16x8;

__device__ __forceinline__ ushort_t f2bf(float f) {
  union { float f; unsigned u; } v; v.f = f;
  unsigned r = v.u + 0x7fffu + ((v.u >> 16) & 1u);
  return (ushort_t)(r >> 16);
}
__device__ __forceinline__ float bf2f(ushort_t u) {
  union { unsigned u; float f; } v; v.u = ((unsigned)u) << 16;
  return v.f;
}

__device__ __forceinline__ void gload_lds16(const void* g, void* l) {
  __builtin_amdgcn_global_load_lds(
      (const __attribute__((address_space(1))) void*)g,
      (__attribute__((address_space(3))) void*)l, 16, 0, 0);
}

// ---------------- weight transpose + cast to bf16 ----------------
struct WtArgs {
  const float* W[5];
  ushort_t* Wt[5];
};

__global__ __launch_bounds__(256) void wtcast(WtArgs a, int n) {
  const int z = blockIdx.z;
  const float* __restrict__ W = a.W[z];
  ushort_t* __restrict__ Wt = a.Wt[z];
  __shared__ float tile[32][33];
  const int tx = threadIdx.x & 31, ty = threadIdx.x >> 5;  // 32 x 8
  const int bx = blockIdx.x, by = blockIdx.y;
#pragma unroll
  for (int r = 0; r < 4; ++r)
    tile[ty + 8 * r][tx] = W[(size_t)(by * 32 + ty + 8 * r) * n + bx * 32 + tx];
  __syncthreads();
#pragma unroll
  for (int r = 0; r < 4; ++r)
    Wt[(size_t)(bx * 32 + ty + 8 * r) * n + by * 32 + tx] = f2bf(tile[tx][ty + 8 * r]);
}

// ---------------- time-shift mix -> bf16 x4 ----------------
__global__ __launch_bounds__(256) void mix_kernel(
    const float* __restrict__ Hd,
    const float* __restrict__ mr, const float* __restrict__ mk,
    const float* __restrict__ mv, const float* __restrict__ mg,
    ushort_t* __restrict__ xr, ushort_t* __restrict__ xk,
    ushort_t* __restrict__ xv, ushort_t* __restrict__ xg,
    int Mrows, int Cc, int Tt) {
  const size_t n8 = (size_t)Mrows * Cc / 8;
  for (size_t idx = (size_t)blockIdx.x * blockDim.x + threadIdx.x; idx < n8;
       idx += (size_t)gridDim.x * blockDim.x) {
    const size_t e = idx * 8;
    const int m = (int)(e / (size_t)Cc);
    const int c = (int)(e % (size_t)Cc);
    const int t = m % Tt;
    f32x4 h0 = *(const f32x4*)&Hd[e];
    f32x4 h1 = *(const f32x4*)&Hd[e + 4];
    f32x4 sA = {0.f, 0.f, 0.f, 0.f}, sB = {0.f, 0.f, 0.f, 0.f};
    if (t != 0) {
      sA = *(const f32x4*)&Hd[e - Cc];
      sB = *(const f32x4*)&Hd[e - Cc + 4];
    }
    f32x4 mA[4], mB[4];
    mA[0] = *(const f32x4*)&mr[c]; mB[0] = *(const f32x4*)&mr[c + 4];
    mA[1] = *(const f32x4*)&mk[c]; mB[1] = *(const f32x4*)&mk[c + 4];
    mA[2] = *(const f32x4*)&mv[c]; mB[2] = *(const f32x4*)&mv[c + 4];
    mA[3] = *(const f32x4*)&mg[c]; mB[3] = *(const f32x4*)&mg[c + 4];
    u16x8 o[4];
#pragma unroll
    for (int w = 0; w < 4; ++w) {
#pragma unroll
      for (int q = 0; q < 4; ++q) {
        o[w][q]     = f2bf(sA[q] + (h0[q] - sA[q]) * mA[w][q]);
        o[w][q + 4] = f2bf(sB[q] + (h1[q] - sB[q]) * mB[w][q]);
      }
    }
    *(u16x8*)&xr[e] = o[0];
    *(u16x8*)&xk[e] = o[1];
    *(u16x8*)&xv[e] = o[2];
    *(u16x8*)&xg[e] = o[3];
  }
}

// ======== 256x256 bf16 GEMM, 16x16x32 MFMA, 1-phase-deep software pipeline ==
// C[M,N] = A[M,K] @ Bt[N,K]^T.  8 waves (2Mx4N), BK=64, 128KB dbuf LDS.
// R1-verified fragment geometry + swizzle (row&7, 0 bank conflicts).
// Pipeline: tile t+1's top fragments (ah0-3, bq0) preloaded under ph3's
// MFMAs; per-phase reads issued BEFORE the phase's MFMA cluster so their
// latency hides under compute.  2 barriers per K-tile:
//   WAR: lgkmcnt(0)+barrier before staging t+2 into the consumed buffer
//   RAW: vmcnt(8)+barrier before touching tile t+1's buffer (counted, never
//        0 in the main loop; 16 outstanding -> wait 8 = exactly t+1 landed).
struct GemmArgs {
  const ushort_t* A[4];
  const ushort_t* Bt[4];
  void* C[4];
};

// Stage one 256x64 A-tile + 256x64 B-tile into ldsbuf (64KB region).
// LDS dest linear (gload_lds requirement); global SOURCE pre-swizzled with the
// same involution the reads use: byte ^= ((row&7)<<4)  (row = byte>>7).
__device__ __forceinline__ void stage_tile(
    const ushort_t* __restrict__ A, const ushort_t* __restrict__ Bt,
    int K, int bm0, int bn0, int k0, char* ldsbuf, int tid) {
#pragma unroll
  for (int mat = 0; mat < 2; ++mat) {
    const ushort_t* src0 = mat ? Bt : A;
    const int r0 = mat ? bn0 : bm0;
#pragma unroll
    for (int hf = 0; hf < 2; ++hf) {
#pragma unroll
      for (int s = 0; s < 2; ++s) {
        const int d0 = (s * 512 + tid) * 16;
        const int sd = d0 ^ (((d0 >> 7) & 7) << 4);
        const ushort_t* src =
            src0 + (size_t)(r0 + hf * 128 + (sd >> 7)) * K + k0 + ((sd & 127) >> 1);
        gload_lds16(src, ldsbuf + mat * 32768 + hf * 16384 + d0);
      }
    }
  }
}

template <int BF16OUT>
__global__ __launch_bounds__(512, 1) void gemm256(GemmArgs args, int M, int N, int K) {
  extern __shared__ char lds[];  // 131072 bytes: 2 bufs x (A 32KB | B 32KB)
  const int z = blockIdx.z;
  const ushort_t* __restrict__ A = args.A[z];
  const ushort_t* __restrict__ Bt = args.Bt[z];

  const int tid = threadIdx.x;
  const int lane = tid & 63, w = tid >> 6;
  const int wm = w >> 2, wn = w & 3;       // 2 x 4 waves
  const int r16 = lane & 15, kb = lane >> 4;

  // XCD-aware bijective swizzle (nwg % 8 == 0 for our shapes)
  const int nbx = N >> 8;
  const int nwg = nbx * (M >> 8);
  const int orig = blockIdx.y * nbx + blockIdx.x;
  const int wid = (orig & 7) * (nwg >> 3) + (orig >> 3);
  const int bm0 = (wid / nbx) << 8;
  const int bn0 = (wid % nbx) << 8;

  // Swizzled LDS byte offsets (ks=0 only; ks=1 = off ^ 64, carry-free since
  // low 7 bits of the unswizzled offset are kb*16 <= 48).
  int aoff[8], boff[4];
#pragma unroll
  for (int mi = 0; mi < 8; ++mi) {
    const int d = (mi * 16 + r16) * 128 + kb * 16;
    aoff[mi] = wm * 16384 + (d ^ (((d >> 7) & 7) << 4));
  }
#pragma unroll
  for (int ni = 0; ni < 4; ++ni) {
    const int d = ((wn & 1) * 64 + ni * 16 + r16) * 128 + kb * 16;
    boff[ni] = 32768 + (wn >> 1) * 16384 + (d ^ (((d >> 7) & 7) << 4));
  }

  f32x4 acc[8][4] = {};
  const int NT = K >> 6;

  // prologue: tiles 0,1 -> bufs 0,1; wait tile0 (8 of 16 loads), tile1 flies
  stage_tile(A, Bt, K, bm0, bn0, 0, lds, tid);
  stage_tile(A, Bt, K, bm0, bn0, 64, lds + 65536, tid);
  asm volatile("s_waitcnt vmcnt(8)" ::: "memory");
  asm volatile("s_barrier" ::: "memory");

  // preload tile-0 top fragments (ah0-3, bq0)
  bf16x8 ah[4][2], bq0[2][2], bq1[2][2], ah2[4][2];
#pragma unroll
  for (int m = 0; m < 4; ++m) {
    ah[m][0] = *(const bf16x8*)(lds + aoff[m]);
    ah[m][1] = *(const bf16x8*)(lds + (aoff[m] ^ 64));
  }
#pragma unroll
  for (int n = 0; n < 2; ++n) {
    bq0[n][0] = *(const bf16x8*)(lds + boff[n]);
    bq0[n][1] = *(const bf16x8*)(lds + (boff[n] ^ 64));
  }

  for (int t = 0; t < NT; ++t) {
    const int cur = t & 1;
    char* cbase = lds + cur * 65536;
    const char* nbase = lds + (cur ^ 1) * 65536;

    // ---- ph0: issue bq1 reads; MFMA (mi 0-3, ni 0-1) on preloaded ah x bq0
#pragma unroll
    for (int n = 0; n < 2; ++n) {
      bq1[n][0] = *(const bf16x8*)(cbase + boff[2 + n]);
      bq1[n][1] = *(const bf16x8*)(cbase + (boff[2 + n] ^ 64));
    }
    __builtin_amdgcn_s_setprio(1);
#pragma unroll
    for (int m = 0; m < 4; ++m)
#pragma unroll
      for (int n = 0; n < 2; ++n)
#pragma unroll
        for (int ks = 0; ks < 2; ++ks)
          acc[m][n] = __builtin_amdgcn_mfma_f32_16x16x32_bf16(
              ah[m][ks], bq0[n][ks], acc[m][n], 0, 0, 0);
    __builtin_amdgcn_s_setprio(0);

    // ---- ph1: issue ah2 reads; MFMA (mi 0-3, ni 2-3) on ah x bq1
#pragma unroll
    for (int m = 0; m < 4; ++m) {
      ah2[m][0] = *(const bf16x8*)(cbase + aoff[4 + m]);
      ah2[m][1] = *(const bf16x8*)(cbase + (aoff[4 + m] ^ 64));
    }
    __builtin_amdgcn_s_setprio(1);
#pragma unroll
    for (int m = 0; m < 4; ++m)
#pragma unroll
      for (int n = 0; n < 2; ++n)
#pragma unroll
        for (int ks = 0; ks < 2; ++ks)
          acc[m][2 + n] = __builtin_amdgcn_mfma_f32_16x16x32_bf16(
              ah[m][ks], bq1[n][ks], acc[m][2 + n], 0, 0, 0);
    __builtin_amdgcn_s_setprio(0);

    // ---- WAR fence: this wave's cbase reads complete, then all waves ----
    asm volatile("s_waitcnt lgkmcnt(0)" ::: "memory");
    asm volatile("s_barrier" ::: "memory");
    if (t + 2 < NT)
      stage_tile(A, Bt, K, bm0, bn0, (t + 2) * 64, cbase, tid);

    // ---- ph2: MFMA (mi 4-7, ni 0-1) on ah2 x bq0 (regs only) ----
    __builtin_amdgcn_s_setprio(1);
#pragma unroll
    for (int m = 0; m < 4; ++m)
#pragma unroll
      for (int n = 0; n < 2; ++n)
#pragma unroll
        for (int ks = 0; ks < 2; ++ks)
          acc[4 + m][n] = __builtin_amdgcn_mfma_f32_16x16x32_bf16(
              ah2[m][ks], bq0[n][ks], acc[4 + m][n], 0, 0, 0);
    __builtin_amdgcn_s_setprio(0);

    // ---- RAW fence: tile t+1 landed everywhere; then preload its top
    //      fragments so they fly under ph3's MFMAs ----
    if (t + 1 < NT) {
      if (t + 2 < NT)
        asm volatile("s_waitcnt vmcnt(8)" ::: "memory");  // t+1 landed; t+2 flies
      else
        asm volatile("s_waitcnt vmcnt(0)" ::: "memory");  // tail drain
      asm volatile("s_barrier" ::: "memory");
#pragma unroll
      for (int m = 0; m < 4; ++m) {
        ah[m][0] = *(const bf16x8*)(nbase + aoff[m]);
        ah[m][1] = *(const bf16x8*)(nbase + (aoff[m] ^ 64));
      }
#pragma unroll
      for (int n = 0; n < 2; ++n) {
        bq0[n][0] = *(const bf16x8*)(nbase + boff[n]);
        bq0[n][1] = *(const bf16x8*)(nbase + (boff[n] ^ 64));
      }
    }

    // ---- ph3: MFMA (mi 4-7, ni 2-3) on ah2 x bq1 (regs only) ----
    __builtin_amdgcn_s_setprio(1);
#pragma unroll
    for (int m = 0; m < 4; ++m)
#pragma unroll
      for (int n = 0; n < 2; ++n)
#pragma unroll
        for (int ks = 0; ks < 2; ++ks)
          acc[4 + m][2 + n] = __builtin_amdgcn_mfma_f32_16x16x32_bf16(
              ah2[m][ks], bq1[n][ks], acc[4 + m][2 + n], 0, 0, 0);
    __builtin_amdgcn_s_setprio(0);
  }

  const int row0 = bm0 + wm * 128 + kb * 4;
  const int col0 = bn0 + wn * 64 + r16;
#pragma unroll
  for (int mi = 0; mi < 8; ++mi)
#pragma unroll
    for (int ni = 0; ni < 4; ++ni) {
      f32x4 v = acc[mi][ni];
      const int row = row0 + mi * 16;
      const int col = col0 + ni * 16;
#pragma unroll
      for (int rr = 0; rr < 4; ++rr) {
        if (BF16OUT)
          ((ushort_t*)args.C[z])[(size_t)(row + rr) * N + col] = f2bf(v[rr]);
        else
          ((float*)args.C[z])[(size_t)(row + rr) * N + col] = v[rr];
      }
    }
}

// ---------------- Phase A: per-chunk WKV scan from S=0 ----------------
__global__ __launch_bounds__(256) void wkv_chunk(
    const ushort_t* __restrict__ Rm, const ushort_t* __restrict__ Km,
    const ushort_t* __restrict__ Vm, const float* __restrict__ td,
    const float* __restrict__ tf,
    float* __restrict__ Oatt, float* __restrict__ chunkA,
    int Tt, int Hh, int NC, int Lc) {
  const int blk = blockIdx.x;
  const int bh = blk / NC, c = blk % NC;
  const int b = bh / Hh, h = bh % Hh;
  const int tid = threadIdx.x, lane = tid & 63, wv = tid >> 6;
  const int jj = lane & 15, iq = lane >> 4;
  const int j = wv * 16 + jj;
  const int Cc = Hh * 64;
  const int ioff = iq * 16;

  float S[16], uu[16], ww[16];
#pragma unroll
  for (int ii = 0; ii < 16; ++ii) {
    const int i = ioff + ii;
    uu[ii] = tf[h * 64 + i];
    ww[ii] = expf(-expf(td[h * 64 + i]));
    S[ii] = 0.f;
  }

  const size_t base = ((size_t)b * Tt + (size_t)c * Lc) * Cc + h * 64;

  u16x8 rA0, rA1, kA0, kA1;
  ushort_t vj;
  rA0 = *(const u16x8*)&Rm[base + ioff];
  rA1 = *(const u16x8*)&Rm[base + ioff + 8];
  kA0 = *(const u16x8*)&Km[base + ioff];
  kA1 = *(const u16x8*)&Km[base + ioff + 8];
  vj = Vm[base + j];

  for (int t = 0; t < Lc; ++t) {
    u16x8 rc0 = rA0, rc1 = rA1, kc0 = kA0, kc1 = kA1;
    const float vc = bf2f(vj);
    if (t + 1 < Lc) {
      const size_t nb = base + (size_t)(t + 1) * Cc;
      rA0 = *(const u16x8*)&Rm[nb + ioff];
      rA1 = *(const u16x8*)&Rm[nb + ioff + 8];
      kA0 = *(const u16x8*)&Km[nb + ioff];
      kA1 = *(const u16x8*)&Km[nb + ioff + 8];
      vj = Vm[nb + j];
    }
    float out = 0.f;
#pragma unroll
    for (int ii = 0; ii < 16; ++ii) {
      const float ri = bf2f(ii < 8 ? rc0[ii] : rc1[ii - 8]);
      const float ki = bf2f(ii < 8 ? kc0[ii] : kc1[ii - 8]);
      const float kv = ki * vc;
      out += ri * fmaf(uu[ii], kv, S[ii]);   // state BEFORE update
      S[ii] = fmaf(ww[ii], S[ii], kv);
    }
    out += __shfl_xor(out, 16);
    out += __shfl_xor(out, 32);
    if (iq == 0) Oatt[base + (size_t)t * Cc + j] = out;
  }

  float* Ac = chunkA + (size_t)blk * 4096;
#pragma unroll
  for (int ii = 0; ii < 16; ++ii)
    Ac[(ioff + ii) * 64 + j] = S[ii];
}

// ---------------- Phase B: sequential carry across chunks ----------------
__global__ __launch_bounds__(256) void chunk_carry(
    const float* __restrict__ chunkA, const float* __restrict__ s0,
    const float* __restrict__ td,
    float* __restrict__ chunkS, float* __restrict__ Sout,
    int Hh, int NC, int Lc) {
  const int blk = blockIdx.x;
  const int bh = blk >> 2, q = blk & 3;
  const int h = bh % Hh;
  const int e4 = q * 1024 + threadIdx.x * 4;
  const int i = e4 >> 6;
  const float wL = expf(-(float)Lc * expf(td[h * 64 + i]));
  f32x4 S = *(const f32x4*)&s0[(size_t)bh * 4096 + e4];
  for (int c = 0; c < NC; ++c) {
    *(f32x4*)&chunkS[((size_t)bh * NC + c) * 4096 + e4] = S;
    f32x4 A = *(const f32x4*)&chunkA[((size_t)bh * NC + c) * 4096 + e4];
#pragma unroll
    for (int t = 0; t < 4; ++t) S[t] = fmaf(wL, S[t], A[t]);
  }
  *(f32x4*)&Sout[(size_t)bh * 4096 + e4] = S;
}

// ---------------- Phase C: inter-chunk contribution + gnorm + gate ----------
__global__ __launch_bounds__(256) void chunk_out(
    const float* __restrict__ OattIn, const float* __restrict__ chunkS,
    const ushort_t* __restrict__ Rm, const ushort_t* __restrict__ Gm,
    const float* __restrict__ td,
    const float* __restrict__ lnw, const float* __restrict__ lnb,
    ushort_t* __restrict__ Xo, int Tt, int Hh, int NC, int Lc) {
  __shared__ float rL[128 * 64];  // r~ = r * w^tau, f32
  const int blk = blockIdx.x;
  const int bh = blk / NC, c = blk % NC;
  const int b = bh / Hh, h = bh % Hh;
  const int tid = threadIdx.x;
  const int Cc = Hh * 64;
  const size_t rowbase = (size_t)b * Tt + (size_t)c * Lc;

  {
    const int i0 = (tid & 7) * 8;
    const int tb = tid >> 3;
    float e8[8];
#pragma unroll
    for (int qq = 0; qq < 8; ++qq) e8[qq] = expf(td[h * 64 + i0 + qq]);
#pragma unroll
    for (int m = 0; m < 4; ++m) {
      const int tau = tb + 32 * m;
      u16x8 rv = *(const u16x8*)&Rm[(rowbase + tau) * Cc + h * 64 + i0];
#pragma unroll
      for (int qq = 0; qq < 8; ++qq)
        rL[tau * 64 + i0 + qq] = bf2f(rv[qq]) * expf(-(float)tau * e8[qq]);
    }
  }

  const int lane = tid & 63, wv = tid >> 6;
  float Sc[64];
  {
    const float* Sp = chunkS + (size_t)blk * 4096 + lane;
#pragma unroll
    for (int i = 0; i < 64; ++i) Sc[i] = Sp[i * 64];
  }
  const float lw = lnw[h * 64 + lane];
  const float lb = lnb[h * 64 + lane];
  __syncthreads();

  for (int k = 0; k < Lc / 4; ++k) {
    const int tau = wv + 4 * k;
    const size_t goff = (rowbase + tau) * Cc + h * 64 + lane;
    float acc = OattIn[goff];
#pragma unroll
    for (int i0 = 0; i0 < 64; i0 += 4) {
      f32x4 rv = *(const f32x4*)&rL[tau * 64 + i0];
      acc = fmaf(rv[0], Sc[i0], acc);
      acc = fmaf(rv[1], Sc[i0 + 1], acc);
      acc = fmaf(rv[2], Sc[i0 + 2], acc);
      acc = fmaf(rv[3], Sc[i0 + 3], acc);
    }
    float s = acc, s2 = acc * acc;
#pragma unroll
    for (int m = 1; m < 64; m <<= 1) {
      s += __shfl_xor(s, m);
      s2 += __shfl_xor(s2, m);
    }
    const float mean = s * (1.f / 64.f);
    const float var = s2 * (1.f / 64.f) - mean * mean;
    const float inv = 1.f / sqrtf(var + 1e-5f);
    const float y = (acc - mean) * inv * lw + lb;
    const float gv = bf2f(Gm[goff]);
    const float gate = gv / (1.f + expf(-gv));
    Xo[goff] = f2bf(y * gate);
  }
}

// ---------------- host launch ----------------
extern "C" void kernel_launch(void* const* d_in, const int* in_sizes, int n_in,
                              void* d_out, int out_size, void* d_ws, size_t ws_size,
                              hipStream_t stream) {
  const int B = 4, T = 2048, Cc = 2048, H = 32;
  const int M = B * T;
  const int NC = 16, Lc = 128;

  const float* hidden = (const float*)d_in[0];
  const float* td     = (const float*)d_in[1];
  const float* tf     = (const float*)d_in[2];
  const float* Wr     = (const float*)d_in[3];
  const float* Wk     = (const float*)d_in[4];
  const float* Wv     = (const float*)d_in[5];
  const float* Wg     = (const float*)d_in[6];
  const float* Wo     = (const float*)d_in[7];
  const float* mix_r  = (const float*)d_in[8];
  const float* mix_k  = (const float*)d_in[9];
  const float* mix_v  = (const float*)d_in[10];
  const float* mix_g  = (const float*)d_in[11];
  const float* lnw    = (const float*)d_in[12];
  const float* lnb    = (const float*)d_in[13];
  const float* s0     = (const float*)d_in[14];

  const size_t SZ_WT = (size_t)Cc * Cc * 2;  // 8 MB
  const size_t SZ_X  = (size_t)M * Cc * 2;   // 32 MB
  const size_t NEED  = 5 * SZ_WT + 6 * SZ_X; // 232 MB

  if (ws_size < NEED) return;  // clean wrong-answer instead of fault

  float* out  = (float*)d_out;                      // [M, C] (final)
  float* sfin = (float*)d_out + (size_t)M * Cc;     // [B,H,64,64] (final)
  ushort_t* xg = (ushort_t*)d_out;                  // scratch in d_out[0,32MB)
  ushort_t* gb = (ushort_t*)d_out + (size_t)M * Cc; // scratch in d_out[32,64MB)

  char* ws = (char*)d_ws;
  ushort_t* wt[5];
  for (int z = 0; z < 5; ++z) wt[z] = (ushort_t*)(ws + z * SZ_WT);
  char* regX = ws + 5 * SZ_WT;   // 96 MB
  char* regY = regX + 3 * SZ_X;  // 96 MB
  ushort_t* xr = (ushort_t*)regX;
  ushort_t* xk = (ushort_t*)(regX + SZ_X);
  ushort_t* xv = (ushort_t*)(regX + 2 * SZ_X);
  ushort_t* rb = (ushort_t*)regY;
  ushort_t* kb = (ushort_t*)(regY + SZ_X);
  ushort_t* vb = (ushort_t*)(regY + 2 * SZ_X);
  float* oatt   = (float*)regX;                 // 64 MB (over xr,xk)
  float* chunkA = (float*)(regX + 2 * SZ_X);    // 32 MB (over xv)
  float* chunkS = (float*)(regY + SZ_X);        // 32 MB (over kb)
  ushort_t* xo  = (ushort_t*)(regY + 2 * SZ_X); // 32 MB (over vb)

  {  // weights: transpose + cast to bf16 [N,K]
    WtArgs a;
    a.W[0] = Wr; a.W[1] = Wk; a.W[2] = Wv; a.W[3] = Wg; a.W[4] = Wo;
    for (int z = 0; z < 5; ++z) a.Wt[z] = wt[z];
    dim3 g(Cc / 32, Cc / 32, 5);
    wtcast<<<g, 256, 0, stream>>>(a, Cc);
  }

  mix_kernel<<<2048, 256, 0, stream>>>(hidden, mix_r, mix_k, mix_v, mix_g,
                                       xr, xk, xv, xg, M, Cc, T);

  {  // r,k,v,g = x_i @ W_i (z-batched, bf16 outputs)
    GemmArgs a;
    a.A[0] = xr; a.A[1] = xk; a.A[2] = xv; a.A[3] = xg;
    for (int z = 0; z < 4; ++z) a.Bt[z] = wt[z];
    a.C[0] = rb; a.C[1] = kb; a.C[2] = vb; a.C[3] = gb;
    dim3 g(Cc / 256, M / 256, 4);
    gemm256<1><<<g, 512, 131072, stream>>>(a, M, Cc, Cc);
  }

  wkv_chunk<<<B * H * NC, 256, 0, stream>>>(rb, kb, vb, td, tf, oatt, chunkA,
                                            T, H, NC, Lc);
  chunk_carry<<<B * H * 4, 256, 0, stream>>>(chunkA, s0, td, chunkS, sfin,
                                             H, NC, Lc);
  chunk_out<<<B * H * NC, 256, 0, stream>>>(oatt, chunkS, rb, gb, td, lnw, lnb,
                                            xo, T, H, NC, Lc);

  {  // out = xo @ Wo (f32 output)
    GemmArgs a = {};
    a.A[0] = xo; a.Bt[0] = wt[4]; a.C[0] = out;
    dim3 g(Cc / 256, M / 256, 1);
    gemm256<0><<<g, 512, 131072, stream>>>(a, M, Cc, Cc);
  }
}

// Round 5
// 702.802 us; speedup vs baseline: 1.3944x; 1.3944x over previous
//
#include <hip/hip_runtime.h>
#include <stdint.h>

typedef unsigned short ushort_t;
typedef __attribute__((ext_vector_type(8))) short bf16x8;
typedef __attribute__((ext_vector_type(4))) float f32x4;
typedef __attribute__((ext_vector_type(8))) unsigned short u16x8;

__device__ __forceinline__ ushort_t f2bf(float f) {
  union { float f; unsigned u; } v; v.f = f;
  unsigned r = v.u + 0x7fffu + ((v.u >> 16) & 1u);
  return (ushort_t)(r >> 16);
}
__device__ __forceinline__ float bf2f(ushort_t u) {
  union { unsigned u; float f; } v; v.u = ((unsigned)u) << 16;
  return v.f;
}

__device__ __forceinline__ void gload_lds16(const void* g, void* l) {
  __builtin_amdgcn_global_load_lds(
      (const __attribute__((address_space(1))) void*)g,
      (__attribute__((address_space(3))) void*)l, 16, 0, 0);
}

// ---------------- weight transpose + cast to bf16 ----------------
struct WtArgs {
  const float* W[5];
  ushort_t* Wt[5];
};

__global__ __launch_bounds__(256) void wtcast(WtArgs a, int n) {
  const int z = blockIdx.z;
  const float* __restrict__ W = a.W[z];
  ushort_t* __restrict__ Wt = a.Wt[z];
  __shared__ float tile[32][33];
  const int tx = threadIdx.x & 31, ty = threadIdx.x >> 5;  // 32 x 8
  const int bx = blockIdx.x, by = blockIdx.y;
#pragma unroll
  for (int r = 0; r < 4; ++r)
    tile[ty + 8 * r][tx] = W[(size_t)(by * 32 + ty + 8 * r) * n + bx * 32 + tx];
  __syncthreads();
#pragma unroll
  for (int r = 0; r < 4; ++r)
    Wt[(size_t)(bx * 32 + ty + 8 * r) * n + by * 32 + tx] = f2bf(tile[tx][ty + 8 * r]);
}

// ---------------- time-shift mix -> bf16 x4 ----------------
__global__ __launch_bounds__(256) void mix_kernel(
    const float* __restrict__ Hd,
    const float* __restrict__ mr, const float* __restrict__ mk,
    const float* __restrict__ mv, const float* __restrict__ mg,
    ushort_t* __restrict__ xr, ushort_t* __restrict__ xk,
    ushort_t* __restrict__ xv, ushort_t* __restrict__ xg,
    int Mrows, int Cc, int Tt) {
  const size_t n8 = (size_t)Mrows * Cc / 8;
  for (size_t idx = (size_t)blockIdx.x * blockDim.x + threadIdx.x; idx < n8;
       idx += (size_t)gridDim.x * blockDim.x) {
    const size_t e = idx * 8;
    const int m = (int)(e / (size_t)Cc);
    const int c = (int)(e % (size_t)Cc);
    const int t = m % Tt;
    f32x4 h0 = *(const f32x4*)&Hd[e];
    f32x4 h1 = *(const f32x4*)&Hd[e + 4];
    f32x4 sA = {0.f, 0.f, 0.f, 0.f}, sB = {0.f, 0.f, 0.f, 0.f};
    if (t != 0) {
      sA = *(const f32x4*)&Hd[e - Cc];
      sB = *(const f32x4*)&Hd[e - Cc + 4];
    }
    f32x4 mA[4], mB[4];
    mA[0] = *(const f32x4*)&mr[c]; mB[0] = *(const f32x4*)&mr[c + 4];
    mA[1] = *(const f32x4*)&mk[c]; mB[1] = *(const f32x4*)&mk[c + 4];
    mA[2] = *(const f32x4*)&mv[c]; mB[2] = *(const f32x4*)&mv[c + 4];
    mA[3] = *(const f32x4*)&mg[c]; mB[3] = *(const f32x4*)&mg[c + 4];
    u16x8 o[4];
#pragma unroll
    for (int w = 0; w < 4; ++w) {
#pragma unroll
      for (int q = 0; q < 4; ++q) {
        o[w][q]     = f2bf(sA[q] + (h0[q] - sA[q]) * mA[w][q]);
        o[w][q + 4] = f2bf(sB[q] + (h1[q] - sB[q]) * mB[w][q]);
      }
    }
    *(u16x8*)&xr[e] = o[0];
    *(u16x8*)&xk[e] = o[1];
    *(u16x8*)&xv[e] = o[2];
    *(u16x8*)&xg[e] = o[3];
  }
}

// ======== 256x256 bf16 GEMM, counted-vmcnt pipeline, XOR-swizzled LDS ========
// C[M,N] = A[M,K] @ Bt[N,K]^T.  8 waves (2Mx4N), BK=64, 128KB dbuf LDS.
// R1-verified schedule (4 phases, ph2-staging, vmcnt(8) never 0 in-loop).
// This round: staging addresses decomposed into wave-uniform base (SGPR) +
// ONE per-thread voffset (identical for all 8 loads: the s/hf deltas are
// uniform and 64 == 0 mod 8 keeps the swizzle slot invariant), and the
// 8-load burst split A-half / B-half around ph2's MFMA cluster so its issue
// cost hides under compute.  LDS image byte-identical to R1.
struct GemmArgs {
  const ushort_t* A[4];
  const ushort_t* Bt[4];
  void* C[4];
};

// Stage one 256x64 tile of one matrix (A or Bt) into ldsmat (32KB region).
// base = mat + r0*K + k0 (wave-uniform).  voff = per-thread element offset
// encoding the source pre-swizzle: row = tid>>3, col-bytes ^= ((row&7)<<4).
__device__ __forceinline__ void stage_mat(const ushort_t* __restrict__ base,
                                          int K, int voff, char* ldsmat,
                                          int tid) {
#pragma unroll
  for (int hf = 0; hf < 2; ++hf)
#pragma unroll
    for (int s = 0; s < 2; ++s)
      gload_lds16(base + (size_t)(hf * 128 + s * 64) * K + voff,
                  ldsmat + hf * 16384 + s * 8192 + tid * 16);
}

template <int BF16OUT>
__global__ __launch_bounds__(512, 1) void gemm256(GemmArgs args, int M, int N, int K) {
  extern __shared__ char lds[];  // 131072 bytes: 2 bufs x (A 32KB | B 32KB)
  const int z = blockIdx.z;
  const ushort_t* __restrict__ A = args.A[z];
  const ushort_t* __restrict__ Bt = args.Bt[z];

  const int tid = threadIdx.x;
  const int lane = tid & 63, w = tid >> 6;
  const int wm = w >> 2, wn = w & 3;       // 2 x 4 waves
  const int r16 = lane & 15, kb = lane >> 4;

  // XCD-aware bijective swizzle (nwg % 8 == 0 for our shapes)
  const int nbx = N >> 8;
  const int nwg = nbx * (M >> 8);
  const int orig = blockIdx.y * nbx + blockIdx.x;
  const int wid = (orig & 7) * (nwg >> 3) + (orig >> 3);
  const int bm0 = (wid / nbx) << 8;
  const int bn0 = (wid % nbx) << 8;

  // Per-thread staging source offset (elements), shared by all 8 gloads.
  const int trow = tid >> 3;  // 0..63
  const int voff = trow * K + (((((tid & 7) * 16) ^ ((trow & 7) << 4))) >> 1);
  const ushort_t* __restrict__ Abase = A + (size_t)bm0 * K;
  const ushort_t* __restrict__ Bbase = Bt + (size_t)bn0 * K;

  // Swizzled LDS byte offsets (ks=0 only; ks=1 = off ^ 64, carry-free since
  // low 7 bits of the unswizzled offset are kb*16 <= 48).
  int aoff[8], boff[4];
#pragma unroll
  for (int mi = 0; mi < 8; ++mi) {
    const int d = (mi * 16 + r16) * 128 + kb * 16;
    aoff[mi] = wm * 16384 + (d ^ (((d >> 7) & 7) << 4));
  }
#pragma unroll
  for (int ni = 0; ni < 4; ++ni) {
    const int d = ((wn & 1) * 64 + ni * 16 + r16) * 128 + kb * 16;
    boff[ni] = 32768 + (wn >> 1) * 16384 + (d ^ (((d >> 7) & 7) << 4));
  }

  f32x4 acc[8][4] = {};
  const int NT = K >> 6;

  // prologue: tiles 0,1 -> bufs 0,1; wait tile0 (8 of 16 loads), tile1 flies
  stage_mat(Abase, K, voff, lds, tid);
  stage_mat(Bbase, K, voff, lds + 32768, tid);
  stage_mat(Abase + 64, K, voff, lds + 65536, tid);
  stage_mat(Bbase + 64, K, voff, lds + 65536 + 32768, tid);
  asm volatile("s_waitcnt vmcnt(8)" ::: "memory");
  asm volatile("s_barrier" ::: "memory");

  for (int t = 0; t < NT; ++t) {
    const int cur = t & 1;
    char* cbase = lds + cur * 65536;
    bf16x8 ah[4][2], bq[4][2];

    // ---- ph0: read A-half0 + B-quad0; MFMA (mi 0-3, ni 0-1) ----
#pragma unroll
    for (int m = 0; m < 4; ++m) {
      ah[m][0] = *(const bf16x8*)(cbase + aoff[m]);
      ah[m][1] = *(const bf16x8*)(cbase + (aoff[m] ^ 64));
    }
#pragma unroll
    for (int n = 0; n < 2; ++n) {
      bq[n][0] = *(const bf16x8*)(cbase + boff[n]);
      bq[n][1] = *(const bf16x8*)(cbase + (boff[n] ^ 64));
    }
    asm volatile("s_barrier" ::: "memory");
    __builtin_amdgcn_s_setprio(1);
#pragma unroll
    for (int m = 0; m < 4; ++m)
#pragma unroll
      for (int n = 0; n < 2; ++n)
#pragma unroll
        for (int ks = 0; ks < 2; ++ks)
          acc[m][n] = __builtin_amdgcn_mfma_f32_16x16x32_bf16(
              ah[m][ks], bq[n][ks], acc[m][n], 0, 0, 0);
    __builtin_amdgcn_s_setprio(0);

    // ---- ph1: read B-quad1; MFMA (mi 0-3, ni 2-3) ----
#pragma unroll
    for (int n = 2; n < 4; ++n) {
      bq[n][0] = *(const bf16x8*)(cbase + boff[n]);
      bq[n][1] = *(const bf16x8*)(cbase + (boff[n] ^ 64));
    }
    asm volatile("s_barrier" ::: "memory");
    __builtin_amdgcn_s_setprio(1);
#pragma unroll
    for (int m = 0; m < 4; ++m)
#pragma unroll
      for (int n = 2; n < 4; ++n)
#pragma unroll
        for (int ks = 0; ks < 2; ++ks)
          acc[m][n] = __builtin_amdgcn_mfma_f32_16x16x32_bf16(
              ah[m][ks], bq[n][ks], acc[m][n], 0, 0, 0);
    __builtin_amdgcn_s_setprio(0);

    // ---- ph2: read A-half1; barrier (buf[cur] fully read); stage t+2
    //      A-half now, B-half after ph2's MFMAs (issue under compute) ----
#pragma unroll
    for (int m = 0; m < 4; ++m) {
      ah[m][0] = *(const bf16x8*)(cbase + aoff[4 + m]);
      ah[m][1] = *(const bf16x8*)(cbase + (aoff[4 + m] ^ 64));
    }
    asm volatile("s_barrier" ::: "memory");
    if (t + 2 < NT)
      stage_mat(Abase + (t + 2) * 64, K, voff, cbase, tid);
    __builtin_amdgcn_s_setprio(1);
#pragma unroll
    for (int m = 0; m < 4; ++m)
#pragma unroll
      for (int n = 0; n < 2; ++n)
#pragma unroll
        for (int ks = 0; ks < 2; ++ks)
          acc[4 + m][n] = __builtin_amdgcn_mfma_f32_16x16x32_bf16(
              ah[m][ks], bq[n][ks], acc[4 + m][n], 0, 0, 0);

    // ---- ph3: stage t+2 B-half; MFMA (mi 4-7, ni 2-3) ----
    if (t + 2 < NT)
      stage_mat(Bbase + (t + 2) * 64, K, voff, cbase + 32768, tid);
#pragma unroll
    for (int m = 0; m < 4; ++m)
#pragma unroll
      for (int n = 2; n < 4; ++n)
#pragma unroll
        for (int ks = 0; ks < 2; ++ks)
          acc[4 + m][n] = __builtin_amdgcn_mfma_f32_16x16x32_bf16(
              ah[m][ks], bq[n][ks], acc[4 + m][n], 0, 0, 0);
    __builtin_amdgcn_s_setprio(0);

    // ---- boundary: t+1 must have landed in buf[cur^1]; t+2 keeps flying ----
    if (t + 1 < NT) {
      if (t + 2 < NT)
        asm volatile("s_waitcnt vmcnt(8)" ::: "memory");  // drain t+1 only
      else
        asm volatile("s_waitcnt vmcnt(0)" ::: "memory");  // tail drain
      asm volatile("s_barrier" ::: "memory");
    }
  }

  const int row0 = bm0 + wm * 128 + kb * 4;
  const int col0 = bn0 + wn * 64 + r16;
#pragma unroll
  for (int mi = 0; mi < 8; ++mi)
#pragma unroll
    for (int ni = 0; ni < 4; ++ni) {
      f32x4 v = acc[mi][ni];
      const int row = row0 + mi * 16;
      const int col = col0 + ni * 16;
#pragma unroll
      for (int rr = 0; rr < 4; ++rr) {
        if (BF16OUT)
          ((ushort_t*)args.C[z])[(size_t)(row + rr) * N + col] = f2bf(v[rr]);
        else
          ((float*)args.C[z])[(size_t)(row + rr) * N + col] = v[rr];
      }
    }
}

// ---------------- Phase A: per-chunk WKV scan from S=0 ----------------
__global__ __launch_bounds__(256) void wkv_chunk(
    const ushort_t* __restrict__ Rm, const ushort_t* __restrict__ Km,
    const ushort_t* __restrict__ Vm, const float* __restrict__ td,
    const float* __restrict__ tf,
    float* __restrict__ Oatt, float* __restrict__ chunkA,
    int Tt, int Hh, int NC, int Lc) {
  const int blk = blockIdx.x;
  const int bh = blk / NC, c = blk % NC;
  const int b = bh / Hh, h = bh % Hh;
  const int tid = threadIdx.x, lane = tid & 63, wv = tid >> 6;
  const int jj = lane & 15, iq = lane >> 4;
  const int j = wv * 16 + jj;
  const int Cc = Hh * 64;
  const int ioff = iq * 16;

  float S[16], uu[16], ww[16];
#pragma unroll
  for (int ii = 0; ii < 16; ++ii) {
    const int i = ioff + ii;
    uu[ii] = tf[h * 64 + i];
    ww[ii] = expf(-expf(td[h * 64 + i]));
    S[ii] = 0.f;
  }

  const size_t base = ((size_t)b * Tt + (size_t)c * Lc) * Cc + h * 64;

  u16x8 rA0, rA1, kA0, kA1;
  ushort_t vj;
  rA0 = *(const u16x8*)&Rm[base + ioff];
  rA1 = *(const u16x8*)&Rm[base + ioff + 8];
  kA0 = *(const u16x8*)&Km[base + ioff];
  kA1 = *(const u16x8*)&Km[base + ioff + 8];
  vj = Vm[base + j];

  for (int t = 0; t < Lc; ++t) {
    u16x8 rc0 = rA0, rc1 = rA1, kc0 = kA0, kc1 = kA1;
    const float vc = bf2f(vj);
    if (t + 1 < Lc) {
      const size_t nb = base + (size_t)(t + 1) * Cc;
      rA0 = *(const u16x8*)&Rm[nb + ioff];
      rA1 = *(const u16x8*)&Rm[nb + ioff + 8];
      kA0 = *(const u16x8*)&Km[nb + ioff];
      kA1 = *(const u16x8*)&Km[nb + ioff + 8];
      vj = Vm[nb + j];
    }
    float out = 0.f;
#pragma unroll
    for (int ii = 0; ii < 16; ++ii) {
      const float ri = bf2f(ii < 8 ? rc0[ii] : rc1[ii - 8]);
      const float ki = bf2f(ii < 8 ? kc0[ii] : kc1[ii - 8]);
      const float kv = ki * vc;
      out += ri * fmaf(uu[ii], kv, S[ii]);   // state BEFORE update
      S[ii] = fmaf(ww[ii], S[ii], kv);
    }
    out += __shfl_xor(out, 16);
    out += __shfl_xor(out, 32);
    if (iq == 0) Oatt[base + (size_t)t * Cc + j] = out;
  }

  float* Ac = chunkA + (size_t)blk * 4096;
#pragma unroll
  for (int ii = 0; ii < 16; ++ii)
    Ac[(ioff + ii) * 64 + j] = S[ii];
}

// ---------------- Phase B: sequential carry across chunks ----------------
__global__ __launch_bounds__(256) void chunk_carry(
    const float* __restrict__ chunkA, const float* __restrict__ s0,
    const float* __restrict__ td,
    float* __restrict__ chunkS, float* __restrict__ Sout,
    int Hh, int NC, int Lc) {
  const int blk = blockIdx.x;
  const int bh = blk >> 2, q = blk & 3;
  const int h = bh % Hh;
  const int e4 = q * 1024 + threadIdx.x * 4;
  const int i = e4 >> 6;
  const float wL = expf(-(float)Lc * expf(td[h * 64 + i]));
  f32x4 S = *(const f32x4*)&s0[(size_t)bh * 4096 + e4];
  for (int c = 0; c < NC; ++c) {
    *(f32x4*)&chunkS[((size_t)bh * NC + c) * 4096 + e4] = S;
    f32x4 A = *(const f32x4*)&chunkA[((size_t)bh * NC + c) * 4096 + e4];
#pragma unroll
    for (int t = 0; t < 4; ++t) S[t] = fmaf(wL, S[t], A[t]);
  }
  *(f32x4*)&Sout[(size_t)bh * 4096 + e4] = S;
}

// ---------------- Phase C: inter-chunk contribution + gnorm + gate ----------
__global__ __launch_bounds__(256) void chunk_out(
    const float* __restrict__ OattIn, const float* __restrict__ chunkS,
    const ushort_t* __restrict__ Rm, const ushort_t* __restrict__ Gm,
    const float* __restrict__ td,
    const float* __restrict__ lnw, const float* __restrict__ lnb,
    ushort_t* __restrict__ Xo, int Tt, int Hh, int NC, int Lc) {
  __shared__ float rL[128 * 64];  // r~ = r * w^tau, f32
  const int blk = blockIdx.x;
  const int bh = blk / NC, c = blk % NC;
  const int b = bh / Hh, h = bh % Hh;
  const int tid = threadIdx.x;
  const int Cc = Hh * 64;
  const size_t rowbase = (size_t)b * Tt + (size_t)c * Lc;

  {
    const int i0 = (tid & 7) * 8;
    const int tb = tid >> 3;
    float e8[8];
#pragma unroll
    for (int qq = 0; qq < 8; ++qq) e8[qq] = expf(td[h * 64 + i0 + qq]);
#pragma unroll
    for (int m = 0; m < 4; ++m) {
      const int tau = tb + 32 * m;
      u16x8 rv = *(const u16x8*)&Rm[(rowbase + tau) * Cc + h * 64 + i0];
#pragma unroll
      for (int qq = 0; qq < 8; ++qq)
        rL[tau * 64 + i0 + qq] = bf2f(rv[qq]) * expf(-(float)tau * e8[qq]);
    }
  }

  const int lane = tid & 63, wv = tid >> 6;
  float Sc[64];
  {
    const float* Sp = chunkS + (size_t)blk * 4096 + lane;
#pragma unroll
    for (int i = 0; i < 64; ++i) Sc[i] = Sp[i * 64];
  }
  const float lw = lnw[h * 64 + lane];
  const float lb = lnb[h * 64 + lane];
  __syncthreads();

  for (int k = 0; k < Lc / 4; ++k) {
    const int tau = wv + 4 * k;
    const size_t goff = (rowbase + tau) * Cc + h * 64 + lane;
    float acc = OattIn[goff];
#pragma unroll
    for (int i0 = 0; i0 < 64; i0 += 4) {
      f32x4 rv = *(const f32x4*)&rL[tau * 64 + i0];
      acc = fmaf(rv[0], Sc[i0], acc);
      acc = fmaf(rv[1], Sc[i0 + 1], acc);
      acc = fmaf(rv[2], Sc[i0 + 2], acc);
      acc = fmaf(rv[3], Sc[i0 + 3], acc);
    }
    float s = acc, s2 = acc * acc;
#pragma unroll
    for (int m = 1; m < 64; m <<= 1) {
      s += __shfl_xor(s, m);
      s2 += __shfl_xor(s2, m);
    }
    const float mean = s * (1.f / 64.f);
    const float var = s2 * (1.f / 64.f) - mean * mean;
    const float inv = 1.f / sqrtf(var + 1e-5f);
    const float y = (acc - mean) * inv * lw + lb;
    const float gv = bf2f(Gm[goff]);
    const float gate = gv / (1.f + expf(-gv));
    Xo[goff] = f2bf(y * gate);
  }
}

// ---------------- host launch ----------------
extern "C" void kernel_launch(void* const* d_in, const int* in_sizes, int n_in,
                              void* d_out, int out_size, void* d_ws, size_t ws_size,
                              hipStream_t stream) {
  const int B = 4, T = 2048, Cc = 2048, H = 32;
  const int M = B * T;
  const int NC = 16, Lc = 128;

  const float* hidden = (const float*)d_in[0];
  const float* td     = (const float*)d_in[1];
  const float* tf     = (const float*)d_in[2];
  const float* Wr     = (const float*)d_in[3];
  const float* Wk     = (const float*)d_in[4];
  const float* Wv     = (const float*)d_in[5];
  const float* Wg     = (const float*)d_in[6];
  const float* Wo     = (const float*)d_in[7];
  const float* mix_r  = (const float*)d_in[8];
  const float* mix_k  = (const float*)d_in[9];
  const float* mix_v  = (const float*)d_in[10];
  const float* mix_g  = (const float*)d_in[11];
  const float* lnw    = (const float*)d_in[12];
  const float* lnb    = (const float*)d_in[13];
  const float* s0     = (const float*)d_in[14];

  const size_t SZ_WT = (size_t)Cc * Cc * 2;  // 8 MB
  const size_t SZ_X  = (size_t)M * Cc * 2;   // 32 MB
  const size_t NEED  = 5 * SZ_WT + 6 * SZ_X; // 232 MB

  if (ws_size < NEED) return;  // clean wrong-answer instead of fault

  float* out  = (float*)d_out;                      // [M, C] (final)
  float* sfin = (float*)d_out + (size_t)M * Cc;     // [B,H,64,64] (final)
  ushort_t* xg = (ushort_t*)d_out;                  // scratch in d_out[0,32MB)
  ushort_t* gb = (ushort_t*)d_out + (size_t)M * Cc; // scratch in d_out[32,64MB)

  char* ws = (char*)d_ws;
  ushort_t* wt[5];
  for (int z = 0; z < 5; ++z) wt[z] = (ushort_t*)(ws + z * SZ_WT);
  char* regX = ws + 5 * SZ_WT;   // 96 MB
  char* regY = regX + 3 * SZ_X;  // 96 MB
  ushort_t* xr = (ushort_t*)regX;
  ushort_t* xk = (ushort_t*)(regX + SZ_X);
  ushort_t* xv = (ushort_t*)(regX + 2 * SZ_X);
  ushort_t* rb = (ushort_t*)regY;
  ushort_t* kb = (ushort_t*)(regY + SZ_X);
  ushort_t* vb = (ushort_t*)(regY + 2 * SZ_X);
  float* oatt   = (float*)regX;                 // 64 MB (over xr,xk)
  float* chunkA = (float*)(regX + 2 * SZ_X);    // 32 MB (over xv)
  float* chunkS = (float*)(regY + SZ_X);        // 32 MB (over kb)
  ushort_t* xo  = (ushort_t*)(regY + 2 * SZ_X); // 32 MB (over vb)

  {  // weights: transpose + cast to bf16 [N,K]
    WtArgs a;
    a.W[0] = Wr; a.W[1] = Wk; a.W[2] = Wv; a.W[3] = Wg; a.W[4] = Wo;
    for (int z = 0; z < 5; ++z) a.Wt[z] = wt[z];
    dim3 g(Cc / 32, Cc / 32, 5);
    wtcast<<<g, 256, 0, stream>>>(a, Cc);
  }

  mix_kernel<<<2048, 256, 0, stream>>>(hidden, mix_r, mix_k, mix_v, mix_g,
                                       xr, xk, xv, xg, M, Cc, T);

  {  // r,k,v,g = x_i @ W_i (z-batched, bf16 outputs)
    GemmArgs a;
    a.A[0] = xr; a.A[1] = xk; a.A[2] = xv; a.A[3] = xg;
    for (int z = 0; z < 4; ++z) a.Bt[z] = wt[z];
    a.C[0] = rb; a.C[1] = kb; a.C[2] = vb; a.C[3] = gb;
    dim3 g(Cc / 256, M / 256, 4);
    gemm256<1><<<g, 512, 131072, stream>>>(a, M, Cc, Cc);
  }

  wkv_chunk<<<B * H * NC, 256, 0, stream>>>(rb, kb, vb, td, tf, oatt, chunkA,
                                            T, H, NC, Lc);
  chunk_carry<<<B * H * 4, 256, 0, stream>>>(chunkA, s0, td, chunkS, sfin,
                                             H, NC, Lc);
  chunk_out<<<B * H * NC, 256, 0, stream>>>(oatt, chunkS, rb, gb, td, lnw, lnb,
                                            xo, T, H, NC, Lc);

  {  // out = xo @ Wo (f32 output)
    GemmArgs a = {};
    a.A[0] = xo; a.Bt[0] = wt[4]; a.C[0] = out;
    dim3 g(Cc / 256, M / 256, 1);
    gemm256<0><<<g, 512, 131072, stream>>>(a, M, Cc, Cc);
  }
}